// Round 6
// baseline (352.147 us; speedup 1.0000x reference)
//
#include <hip/hip_runtime.h>
#include <hip/hip_bf16.h>
#include <stdint.h>

typedef __hip_bfloat16 bf16;
typedef __attribute__((ext_vector_type(8))) short bf16x8;   // 8 bf16 = 4 VGPRs
typedef __attribute__((ext_vector_type(4))) float f32x4;

#define MFMA16 __builtin_amdgcn_mfma_f32_16x16x32_bf16

// async global->LDS, 16B/lane; LDS dest = wave-uniform base + lane*16
__device__ __forceinline__ void gll16(const bf16* g, const bf16* l) {
    __builtin_amdgcn_global_load_lds(
        (const __attribute__((address_space(1))) void*)g,
        (__attribute__((address_space(3))) void*)(bf16*)l, 16, 0, 0);
}

__device__ __forceinline__ short f2b(float x) {
    bf16 h = __float2bfloat16(x);
    return *reinterpret_cast<short*>(&h);
}
__device__ __forceinline__ float b2f(short s) {
    union { uint32_t u; float f; } cv;
    cv.u = ((uint32_t)(uint16_t)s) << 16;
    return cv.f;
}

// ---------------------------------------------------------------------------
// fp32 -> bf16: one kernel for x + Wq + Wk + Wv (block-range dispatch)
// ---------------------------------------------------------------------------
__global__ void cvt4(const float* __restrict__ x,  const float* __restrict__ wq,
                     const float* __restrict__ wk, const float* __restrict__ wv,
                     bf16* __restrict__ xb, bf16* __restrict__ w1,
                     bf16* __restrict__ w2, bf16* __restrict__ w3)
{
    int b = blockIdx.x;
    const float* s; bf16* d; int base;
    if      (b < 4096) { s = x;  d = xb; base = b; }
    else if (b < 6144) { s = wq; d = w1; base = b - 4096; }
    else if (b < 8192) { s = wk; d = w2; base = b - 6144; }
    else               { s = wv; d = w3; base = b - 8192; }
    int i = base * 2048 + threadIdx.x * 8;
    float4 a = *(const float4*)(s + i);
    float4 c = *(const float4*)(s + i + 4);
    bf16x8 v;
    v[0] = f2b(a.x); v[1] = f2b(a.y); v[2] = f2b(a.z); v[3] = f2b(a.w);
    v[4] = f2b(c.x); v[5] = f2b(c.y); v[6] = f2b(c.z); v[7] = f2b(c.w);
    *(bf16x8*)(d + i) = v;
}
__global__ void cvt1(const float* __restrict__ s, bf16* __restrict__ d) {
    int i = blockIdx.x * 2048 + threadIdx.x * 8;
    float4 a = *(const float4*)(s + i);
    float4 c = *(const float4*)(s + i + 4);
    bf16x8 v;
    v[0] = f2b(a.x); v[1] = f2b(a.y); v[2] = f2b(a.z); v[3] = f2b(a.w);
    v[4] = f2b(c.x); v[5] = f2b(c.y); v[6] = f2b(c.z); v[7] = f2b(c.w);
    *(bf16x8*)(d + i) = v;
}

// ---------------------------------------------------------------------------
// GEMM core: acc[4][4] += A-tile(128 rows @ m0) . B-tile(128 rows @ n0)^T.
// XOR-swizzled unpadded LDS [128][64]: chunk (r,c) stored at (r, c^(r&7)).
// ---------------------------------------------------------------------------
__device__ __forceinline__ void gemm_core(const bf16* __restrict__ A,
                                          const bf16* __restrict__ Bw, int K,
                                          int m0, int n0,
                                          bf16* As, bf16* Bs, f32x4 acc[4][4])
{
    const int t    = threadIdx.x;
    const int wave = t >> 6;
    const int lane = t & 63;
    const int lr   = lane & 15;
    const int lq   = lane >> 4;
    const int wm   = (wave >> 1) * 64;
    const int wn   = (wave & 1) * 64;
    const int r8   = lane >> 3;            // staging row-in-8
    const int c8   = lane & 7;             // staging chunk
    const int gly  = ((c8 ^ r8) << 3);     // swizzled global col (elems)

    const bf16* Ag = A  + (size_t)(m0 + wave * 32 + r8) * K + gly;
    const bf16* Bg = Bw + (size_t)(n0 + wave * 32 + r8) * K + gly;
    bf16* AsW = As + wave * 32 * 64;
    bf16* BsW = Bs + wave * 32 * 64;
    const int sw0 = ((lq ^ (lr & 7)) << 3);         // kk=0  read swizzle
    const int sw1 = (((4 + lq) ^ (lr & 7)) << 3);   // kk=32

    for (int k0 = 0; k0 < K; k0 += 64) {
        __syncthreads();
#pragma unroll
        for (int c = 0; c < 4; ++c) {
            gll16(Ag + (size_t)(c * 8) * K + k0, AsW + c * 512);
            gll16(Bg + (size_t)(c * 8) * K + k0, BsW + c * 512);
        }
        __syncthreads();
#pragma unroll
        for (int kk = 0; kk < 2; ++kk) {
            const int sw = kk ? sw1 : sw0;
            bf16x8 af[4], bfr[4];
#pragma unroll
            for (int i = 0; i < 4; ++i)
                af[i] = *(const bf16x8*)(&As[(wm + i * 16 + lr) * 64 + sw]);
#pragma unroll
            for (int j = 0; j < 4; ++j)
                bfr[j] = *(const bf16x8*)(&Bs[(wn + j * 16 + lr) * 64 + sw]);
#pragma unroll
            for (int i = 0; i < 4; ++i)
#pragma unroll
                for (int j = 0; j < 4; ++j)
                    acc[i][j] = MFMA16(af[i], bfr[j], acc[i][j], 0, 0, 0);
        }
    }
}

// ---------------------------------------------------------------------------
// Fused QKV projection: grid (32, 48); blockIdx.y>>4 selects Wq/Wk/Wv.
// ---------------------------------------------------------------------------
__global__ __launch_bounds__(256, 2)
void gemm_qkv(const bf16* __restrict__ A,
              const bf16* __restrict__ Wq, const bf16* __restrict__ Wk,
              const bf16* __restrict__ Wv,
              bf16* __restrict__ Qo, bf16* __restrict__ Ko, bf16* __restrict__ Vo)
{
    __shared__ bf16 As[128 * 64];
    __shared__ bf16 Bs[128 * 64];
    const int sel = blockIdx.y >> 4;
    const int n0  = (blockIdx.y & 15) * 128;
    const int m0  = blockIdx.x * 128;
    const bf16* Bw = sel == 0 ? Wq : sel == 1 ? Wk : Wv;
    bf16* Cv = sel == 0 ? Qo : sel == 1 ? Ko : Vo;

    f32x4 acc[4][4];
#pragma unroll
    for (int i = 0; i < 4; ++i)
#pragma unroll
        for (int j = 0; j < 4; ++j) acc[i][j] = (f32x4)0.0f;

    gemm_core(A, Bw, 2048, m0, n0, As, Bs, acc);

    const int t = threadIdx.x, wave = t >> 6, lane = t & 63;
    const int lr = lane & 15, lq = lane >> 4;
    const int wm = (wave >> 1) * 64, wn = (wave & 1) * 64;
#pragma unroll
    for (int i = 0; i < 4; ++i) {
        const int mb = m0 + wm + i * 16 + lq * 4;
#pragma unroll
        for (int j = 0; j < 4; ++j) {
            const int n = n0 + wn + j * 16 + lr;
            const int h_ = n >> 7, d_ = n & 127;
            if (sel == 2) {
                const int b_ = mb >> 11, s_ = mb & 2047;
                bf16 pk[4];
#pragma unroll
                for (int r = 0; r < 4; ++r) pk[r] = __float2bfloat16(acc[i][j][r]);
                *(uint2*)(Cv + (size_t)(((b_ << 4) + h_) * 128 + d_) * 2048 + s_) =
                    *(const uint2*)pk;
            } else {
#pragma unroll
                for (int r = 0; r < 4; ++r) {
                    const int m = mb + r;
                    const int b_ = m >> 11, s_ = m & 2047;
                    Cv[(size_t)(((b_ << 4) + h_) * 2048 + s_) * 128 + d_] =
                        __float2bfloat16(acc[i][j][r]);
                }
            }
        }
    }
}

// ---------------------------------------------------------------------------
// Output projection: C(fp32)[M,N] = A(bf16) . Wo(bf16)^T
// ---------------------------------------------------------------------------
__global__ __launch_bounds__(256, 2)
void gemm_o(const bf16* __restrict__ A, const bf16* __restrict__ Bw,
            float* __restrict__ C, int N)
{
    __shared__ bf16 As[128 * 64];
    __shared__ bf16 Bs[128 * 64];
    const int m0 = blockIdx.x * 128;
    const int n0 = blockIdx.y * 128;

    f32x4 acc[4][4];
#pragma unroll
    for (int i = 0; i < 4; ++i)
#pragma unroll
        for (int j = 0; j < 4; ++j) acc[i][j] = (f32x4)0.0f;

    gemm_core(A, Bw, 2048, m0, n0, As, Bs, acc);

    const int t = threadIdx.x, wave = t >> 6, lane = t & 63;
    const int lr = lane & 15, lq = lane >> 4;
    const int wm = (wave >> 1) * 64, wn = (wave & 1) * 64;
#pragma unroll
    for (int i = 0; i < 4; ++i) {
        const int mb = m0 + wm + i * 16 + lq * 4;
#pragma unroll
        for (int j = 0; j < 4; ++j) {
            const int n = n0 + wn + j * 16 + lr;
#pragma unroll
            for (int r = 0; r < 4; ++r)
                C[(size_t)(mb + r) * N + n] = acc[i][j][r];
        }
    }
}

// ---------------------------------------------------------------------------
// Causal flash attention, S^T form, 32 q per wave (2x LDS-read reuse).
// Q,K: [B,H,S,D]; V: [B,H,D,S]; O: [B,S,E] bf16.
// Block 256 thr / 4 waves; q-tile 128 (wave owns 32 q as 2 groups of 16);
// kv-tile 64, K/V double-buffered, XOR-swizzled LDS, gll16 staging.
// Per tile per wave: 36 ds_read_b128-class reads feed 64 MFMAs.
// LDS: 2*Ks(16K) + 2*Vs(16K) + Pb 4x[32][64] (16K) = 80 KB -> 2 blocks/CU.
// ---------------------------------------------------------------------------
__global__ __launch_bounds__(256, 2)
void attn_fwd(const bf16* __restrict__ Q, const bf16* __restrict__ K,
              const bf16* __restrict__ V, bf16* __restrict__ O)
{
    __shared__ bf16 smem[40960];              // 80 KB
    bf16* Ks0 = smem;                         // [64][128] swizzled
    bf16* Ks1 = smem + 8192;
    bf16* Vs0 = smem + 16384;                 // [128][64] swizzled
    bf16* Vs1 = smem + 24576;
    bf16* Pb  = smem + 32768;                 // per-wave [32][64] swizzled

    const int t    = threadIdx.x;
    const int wave = t >> 6;
    const int lane = t & 63;
    const int lr   = lane & 15;
    const int lq   = lane >> 4;

    const int bid  = blockIdx.x;
    const int half = bid >> 8;
    const int idx  = bid & 255;
    const int bh   = idx & 31;                // b*16 + h
    const int qtl  = idx >> 5;
    const int qt   = half ? (15 - qtl) : qtl; // pair-sum balance

    const int bhS   = bh * 2048;
    const int q0    = qt * 128;
    const int qbase = q0 + wave * 32;         // wave's 32 q rows

    const float scale = 0.08838834764831845f; // 1/sqrt(128)
    const float L2E   = 1.4426950408889634f;
    const float SC    = scale * L2E;

    // Q fragments (B-operand), 2 groups of 16 q, pre-scaled by scale*log2e
    bf16x8 aq[2][4];
#pragma unroll
    for (int g = 0; g < 2; ++g) {
        const bf16* qp = Q + (size_t)(bhS + qbase + g * 16 + lr) * 128 + lq * 8;
#pragma unroll
        for (int ks = 0; ks < 4; ++ks) {
            bf16x8 v = *(const bf16x8*)(qp + ks * 32);
#pragma unroll
            for (int e = 0; e < 8; ++e) v[e] = f2b(b2f(v[e]) * SC);
            aq[g][ks] = v;
        }
    }

    // K staging: wave covers kv rows [wave*16, +16), call c -> rows +c*4
    const int krr = lane >> 4;                // 0..3 row within 4
    int swk[4];
    const bf16* Kp[4];
#pragma unroll
    for (int c = 0; c < 4; ++c) {
        swk[c] = (((lane & 15) ^ ((c * 4 + krr) & 7)) << 3);
        Kp[c] = K + (size_t)(bhS + wave * 16 + c * 4 + krr) * 128 + swk[c];
    }
    // V staging: wave covers d rows [wave*32, +32), call c -> rows +c*8
    const bf16* Vp = V + (size_t)(bh * 128 + wave * 32 + (lane >> 3)) * 2048
                       + (((lane & 7) ^ (lane >> 3)) << 3);

    // read-side swizzles: global chunk (ks*4+lq) of row with row&7 == lr&7
    int swz[4];
#pragma unroll
    for (int ks = 0; ks < 4; ++ks) swz[ks] = (((ks * 4 + lq) ^ (lr & 7)) << 3);
    // Pb write offsets: kv chunk (j*2 + lq>>1) ^ (lr&7), half lq&1
    int pw[4];
#pragma unroll
    for (int j = 0; j < 4; ++j)
        pw[j] = ((((j * 2) + (lq >> 1)) ^ (lr & 7)) << 3) + ((lq & 1) << 2);
    bf16* PbW = Pb + wave * 2048;             // this wave's [32][64]

    f32x4 acc_o[2][8];
#pragma unroll
    for (int g = 0; g < 2; ++g)
#pragma unroll
        for (int i = 0; i < 8; ++i) acc_o[g][i] = (f32x4)0.0f;
    float mrow[2] = {-INFINITY, -INFINITY}, lrow[2] = {0.0f, 0.0f};

    const int nkv = 2 * (qt + 1);

    // stage tile 0 into buffer 0
    {
        bf16* Kd = Ks0 + wave * 2048;
        bf16* Vd = Vs0 + wave * 2048;
#pragma unroll
        for (int c = 0; c < 4; ++c) {
            gll16(Kp[c], Kd + c * 512);
            gll16(Vp + c * 16384, Vd + c * 512);
        }
    }

    for (int tile = 0; tile < nkv; ++tile) {
        __syncthreads();                      // loads landed; prev reads done
        const int cur = tile & 1;
        const bf16* KsC = cur ? Ks1 : Ks0;
        const bf16* VsC = cur ? Vs1 : Vs0;
        if (tile + 1 < nkv) {
            bf16* Kd = (cur ? Ks0 : Ks1) + wave * 2048;
            bf16* Vd = (cur ? Vs0 : Vs1) + wave * 2048;
            const size_t ko = (size_t)(tile + 1) * 8192;   // 64*128
            const int    vo = (tile + 1) * 64;
#pragma unroll
            for (int c = 0; c < 4; ++c) {
                gll16(Kp[c] + ko, Kd + c * 512);
                gll16(Vp + c * 16384 + vo, Vd + c * 512);
            }
        }

        // ---- S^T = K.Q^T : acc_s[g][j], kv = j*16 + lq*4 + r ----
        f32x4 acc_s[2][4];
#pragma unroll
        for (int g = 0; g < 2; ++g)
#pragma unroll
            for (int j = 0; j < 4; ++j) acc_s[g][j] = (f32x4)0.0f;
#pragma unroll
        for (int ks = 0; ks < 4; ++ks) {
#pragma unroll
            for (int j = 0; j < 4; ++j) {
                bf16x8 ak = *(const bf16x8*)(&KsC[(j * 16 + lr) * 128 + swz[ks]]);
                acc_s[0][j] = MFMA16(ak, aq[0][ks], acc_s[0][j], 0, 0, 0);
                acc_s[1][j] = MFMA16(ak, aq[1][ks], acc_s[1][j], 0, 0, 0);
            }
        }

        const int kv0 = tile * 64;
        if (kv0 + 63 > qbase) {               // diagonal-straddling tiles only
#pragma unroll
            for (int g = 0; g < 2; ++g) {
                const int q_g = qbase + g * 16 + lr;
#pragma unroll
                for (int j = 0; j < 4; ++j)
#pragma unroll
                    for (int r = 0; r < 4; ++r) {
                        const int kvg = kv0 + j * 16 + lq * 4 + r;
                        if (kvg > q_g) acc_s[g][j][r] = -1e30f;
                    }
            }
        }

        // ---- online softmax (log2 domain); lane owns 2 q columns ----
#pragma unroll
        for (int g = 0; g < 2; ++g) {
            float mx = -1e30f;
#pragma unroll
            for (int j = 0; j < 4; ++j)
#pragma unroll
                for (int r = 0; r < 4; ++r) mx = fmaxf(mx, acc_s[g][j][r]);
            mx = fmaxf(mx, __shfl_xor(mx, 16));
            mx = fmaxf(mx, __shfl_xor(mx, 32));
            const float mnew  = fmaxf(mrow[g], mx);
            const float alpha = exp2f(mrow[g] - mnew);
            mrow[g] = mnew;

            float rs = 0.0f;
#pragma unroll
            for (int j = 0; j < 4; ++j) {
                bf16 pk[4];
#pragma unroll
                for (int r = 0; r < 4; ++r) {
                    float p = exp2f(acc_s[g][j][r] - mnew);
                    rs += p;
                    pk[r] = __float2bfloat16(p);
                }
                *(uint2*)(PbW + (g * 16 + lr) * 64 + pw[j]) = *(const uint2*)pk;
            }
            rs += __shfl_xor(rs, 16);
            rs += __shfl_xor(rs, 32);
            lrow[g] = lrow[g] * alpha + rs;
#pragma unroll
            for (int i = 0; i < 8; ++i)
#pragma unroll
                for (int r = 0; r < 4; ++r) acc_o[g][i][r] *= alpha;
        }

        // ---- O^T += V^T . P^T (same-wave Pb write->read) ----
#pragma unroll
        for (int ks = 0; ks < 2; ++ks) {
            bf16x8 bp0 = *(const bf16x8*)(PbW + lr * 64 + swz[ks]);
            bf16x8 bp1 = *(const bf16x8*)(PbW + (16 + lr) * 64 + swz[ks]);
#pragma unroll
            for (int i = 0; i < 8; ++i) {
                bf16x8 av = *(const bf16x8*)(&VsC[(i * 16 + lr) * 64 + swz[ks]]);
                acc_o[0][i] = MFMA16(av, bp0, acc_o[0][i], 0, 0, 0);
                acc_o[1][i] = MFMA16(av, bp1, acc_o[1][i], 0, 0, 0);
            }
        }
    }

    // ---- epilogue: transpose O^T through LDS, coalesced 16B stores ----
    __syncthreads();
    bf16* OtW = smem + wave * 32 * 136;       // per-wave [32][136]
#pragma unroll
    for (int g = 0; g < 2; ++g) {
        const float inv = 1.0f / lrow[g];
#pragma unroll
        for (int i = 0; i < 8; ++i) {
            bf16 pk[4];
#pragma unroll
            for (int r = 0; r < 4; ++r) pk[r] = __float2bfloat16(acc_o[g][i][r] * inv);
            *(uint2*)(OtW + (g * 16 + lr) * 136 + i * 16 + lq * 4) = *(const uint2*)pk;
        }
    }
    __builtin_amdgcn_s_waitcnt(0);            // drain LDS writes (same wave)
    const int b_ = bh >> 4, h_ = bh & 15;
    const int ro = lane >> 1;                 // 0..31 q row within wave tile
    const int dc = (lane & 1) * 64;           // d chunk
    const bf16* src = OtW + ro * 136 + dc;
    bf16* dst = O + (size_t)(b_ * 2048 + q0 + wave * 32 + ro) * 2048 + h_ * 128 + dc;
#pragma unroll
    for (int u = 0; u < 8; ++u)
        *(uint4*)(dst + u * 8) = *(const uint4*)(src + u * 8);
}

extern "C" void kernel_launch(void* const* d_in, const int* in_sizes, int n_in,
                              void* d_out, int out_size, void* d_ws, size_t ws_size,
                              hipStream_t stream)
{
    const float* x  = (const float*)d_in[0];
    const float* Wq = (const float*)d_in[1];
    const float* Wk = (const float*)d_in[2];
    const float* Wv = (const float*)d_in[3];
    const float* Wo = (const float*)d_in[4];
    float* out = (float*)d_out;

    const size_t NX = 8388608;            // B*S*E
    const size_t NW = 4194304;            // E*E
    bf16* Xb = (bf16*)d_ws;               // [B*S, E]; reused as AO after QKV
    bf16* W1 = Xb + NX;                   // Wq, later Wo
    bf16* W2 = W1 + NW;                   // Wk
    bf16* W3 = W2 + NW;                   // Wv
    bf16* Qb = W3 + NW;                   // [B,H,S,D]
    bf16* Kb = Qb + NX;                   // [B,H,S,D]
    bf16* Vb = Kb + NX;                   // [B,H,D,S]
    bf16* AO = Xb;

    cvt4<<<dim3(10240), dim3(256), 0, stream>>>(x, Wq, Wk, Wv, Xb, W1, W2, W3);
    gemm_qkv<<<dim3(32, 48), dim3(256), 0, stream>>>(Xb, W1, W2, W3, Qb, Kb, Vb);
    cvt1<<<dim3(2048), dim3(256), 0, stream>>>(Wo, W1);
    attn_fwd<<<dim3(512), dim3(256), 0, stream>>>(Qb, Kb, Vb, AO);
    gemm_o<<<dim3(32, 16), dim3(256), 0, stream>>>(AO, W1, out, 2048);
}